// Round 2
// baseline (1678.336 us; speedup 1.0000x reference)
//
#include <hip/hip_runtime.h>

#define HN 128
#define NNODES 100000
#define NEDGES 600000

typedef __attribute__((ext_vector_type(8))) short short8;
typedef __attribute__((ext_vector_type(4))) float f32x4;

// ---------- bf16 split helpers (x ~= hi + lo, dropped term ~2^-16 rel) ----------
__device__ __forceinline__ unsigned short f2bf(float x) {
    unsigned u = __float_as_uint(x);
    u += 0x7FFFu + ((u >> 16) & 1u);   // round-to-nearest-even
    return (unsigned short)(u >> 16);
}
__device__ __forceinline__ float bf2f(unsigned short h) {
    return __uint_as_float(((unsigned)h) << 16);
}

__device__ __forceinline__ f32x4 mfma16(short8 a, short8 b, f32x4 c) {
    return __builtin_amdgcn_mfma_f32_16x16x32_bf16(a, b, c, 0, 0, 0);
}

__device__ __forceinline__ void split_frag(const float xs[8], short8 &hi, short8 &lo) {
    #pragma unroll
    for (int e = 0; e < 8; ++e) {
        unsigned short h = f2bf(xs[e]);
        hi[e] = (short)h;
        lo[e] = (short)f2bf(xs[e] - bf2f(h));
    }
}

// A-frag layout (mfma_f32_16x16x32_bf16): row = lane&15, k = 8*(lane>>4)+e (+32*t)
__device__ __forceinline__ void load_frags_global(const float* __restrict__ row,
                                                  short8 ahi[4], short8 alo[4], int g) {
    #pragma unroll
    for (int t = 0; t < 4; ++t) {
        float4 v0 = *(const float4*)(row + 32*t + 8*g);
        float4 v1 = *(const float4*)(row + 32*t + 8*g + 4);
        float xs[8] = {v0.x, v0.y, v0.z, v0.w, v1.x, v1.y, v1.z, v1.w};
        split_frag(xs, ahi[t], alo[t]);
    }
}

// one 128x128 layer on TWO 16-row A-tiles sharing each B-frag load (bf16x3 emulated fp32)
__device__ __forceinline__ void mlp_layer2(f32x4 C[2][8],
                                           const short8 ahi[2][4], const short8 alo[2][4],
                                           const unsigned short* __restrict__ Whi,
                                           const unsigned short* __restrict__ Wlo,
                                           int mat, int lane) {
    #pragma unroll
    for (int t = 0; t < 4; ++t) {
        #pragma unroll
        for (int n = 0; n < 8; ++n) {
            size_t idx = ((size_t)((mat*32 + t*8 + n)*64 + lane)) * 8;
            short8 bh = *(const short8*)(Whi + idx);
            short8 bl = *(const short8*)(Wlo + idx);
            #pragma unroll
            for (int i = 0; i < 2; ++i) {
                f32x4 a = C[i][n];
                a = mfma16(ahi[i][t], bh, a);
                a = mfma16(ahi[i][t], bl, a);
                a = mfma16(alo[i][t], bh, a);
                C[i][n] = a;
            }
        }
    }
}

// C/D layout: col = lane&15 (+16n), row = 4*(lane>>4)+j.  XOR-swizzled f32 LDS transpose.
// buf is PER-WAVE (8KB) -> no __syncthreads needed; DS ops retire in order within a wave.
__device__ __forceinline__ void c_to_lds(float* buf, const f32x4 C[8], int g, int c) {
    #pragma unroll
    for (int n = 0; n < 8; ++n) {
        #pragma unroll
        for (int j = 0; j < 4; ++j) {
            int row = 4*g + j;
            int col = 16*n + c;
            buf[(row*HN + col) ^ ((row & 7) << 2)] = C[n][j];
        }
    }
}
__device__ __forceinline__ void lds_to_frags(const float* buf, short8 ahi[4], short8 alo[4],
                                             int g, int c) {
    #pragma unroll
    for (int t = 0; t < 4; ++t) {
        int w0 = c*HN + 32*t + 8*g;
        int x  = (c & 7) << 2;
        float4 v0 = *(const float4*)(buf + (w0 ^ x));
        float4 v1 = *(const float4*)(buf + ((w0 + 4) ^ x));
        float xs[8] = {v0.x, v0.y, v0.z, v0.w, v1.x, v1.y, v1.z, v1.w};
        split_frag(xs, ahi[t], alo[t]);
    }
}

__device__ __forceinline__ void add_bias_act(f32x4 C[8], const float* __restrict__ b,
                                             int c, bool do_relu) {
    #pragma unroll
    for (int n = 0; n < 8; ++n) {
        float bv = b[16*n + c];
        #pragma unroll
        for (int j = 0; j < 4; ++j) {
            float v = C[n][j] + bv;
            C[n][j] = do_relu ? fmaxf(v, 0.0f) : v;
        }
    }
}

__device__ __forceinline__ void apply_ln(f32x4 C[8], const float* __restrict__ gamma,
                                         const float* __restrict__ beta, int c) {
    float s1[4] = {0.f,0.f,0.f,0.f}, s2[4] = {0.f,0.f,0.f,0.f};
    #pragma unroll
    for (int n = 0; n < 8; ++n)
        #pragma unroll
        for (int j = 0; j < 4; ++j) { float v = C[n][j]; s1[j] += v; s2[j] += v*v; }
    #pragma unroll
    for (int m = 1; m < 16; m <<= 1) {
        #pragma unroll
        for (int j = 0; j < 4; ++j) {
            s1[j] += __shfl_xor(s1[j], m);
            s2[j] += __shfl_xor(s2[j], m);
        }
    }
    float mn[4], rs[4];
    #pragma unroll
    for (int j = 0; j < 4; ++j) {
        mn[j] = s1[j] * (1.0f/128.0f);
        float var = s2[j] * (1.0f/128.0f) - mn[j]*mn[j];
        rs[j] = rsqrtf(var + 1e-5f);
    }
    #pragma unroll
    for (int n = 0; n < 8; ++n) {
        float ga = gamma[16*n + c], be = beta[16*n + c];
        #pragma unroll
        for (int j = 0; j < 4; ++j)
            C[n][j] = (C[n][j] - mn[j]) * rs[j] * ga + be;
    }
}

// ---------------- weight prep: 11 matrices of [128,128] -> B-frag layout ----------------
// mat ids: 0=ew0[256:384] 1=ew1 2=ew2 3=ew3 | 4=nw0[128:256] 5=nw1 6=nw2 7=nw3
//          8=ew0[0:128](Ps) 9=ew0[128:256](Pr) 10=nw0[0:128](Pn)
// frag idx = ((mat*32 + t*8 + n)*64 + lane)*8 + e ; value = W[32t + 8*(lane>>4)+e][16n + (lane&15)]
__global__ void prep_weights(const float* __restrict__ ew0, const float* __restrict__ ew1,
                             const float* __restrict__ ew2, const float* __restrict__ ew3,
                             const float* __restrict__ nw0, const float* __restrict__ nw1,
                             const float* __restrict__ nw2, const float* __restrict__ nw3,
                             unsigned short* __restrict__ Whi, unsigned short* __restrict__ Wlo) {
    int gid = blockIdx.x * blockDim.x + threadIdx.x;
    if (gid >= 11*2048) return;
    int lane = gid & 63;
    int n = (gid >> 6) & 7;
    int t = (gid >> 9) & 3;
    int m = gid >> 11;
    const float* src; int roff = 0;
    switch (m) {
        case 0: src = ew0; roff = 256; break;
        case 1: src = ew1; break;
        case 2: src = ew2; break;
        case 3: src = ew3; break;
        case 4: src = nw0; roff = 128; break;
        case 5: src = nw1; break;
        case 6: src = nw2; break;
        case 7: src = nw3; break;
        case 8: src = ew0; roff = 0; break;
        case 9: src = ew0; roff = 128; break;
        default: src = nw0; roff = 0; break;
    }
    int col = 16*n + (lane & 15);
    int rbase = roff + 32*t + 8*(lane >> 4);
    size_t o = (size_t)gid * 8;
    #pragma unroll
    for (int e = 0; e < 8; ++e) {
        float x = src[(size_t)(rbase + e) * HN + col];
        unsigned short h = f2bf(x);
        Whi[o + e] = h;
        Wlo[o + e] = f2bf(x - bf2f(h));
    }
}

// ---------------- pre-GEMM: Ps = na@W0a+eb0, Pr = na@W0b, Pn = na@nw0a+nb0 ----------------
// 32 rows/wave, weights loaded once per (mat) for both tiles. No barriers -> early-out safe.
__global__ __launch_bounds__(256, 2)
void pre_kernel(const float* __restrict__ na, const float* __restrict__ eb0,
                const float* __restrict__ nb0,
                const unsigned short* __restrict__ Whi, const unsigned short* __restrict__ Wlo,
                float* __restrict__ Ps, float* __restrict__ Pr, float* __restrict__ Pn) {
    int w = threadIdx.x >> 6, lane = threadIdx.x & 63;
    int g = lane >> 4, c = lane & 15;
    int n0 = (blockIdx.x * 4 + w) * 32;
    if (n0 >= NNODES) return;

    short8 ahi[2][4], alo[2][4];
    load_frags_global(na + (size_t)(n0 + c) * HN, ahi[0], alo[0], g);
    load_frags_global(na + (size_t)(n0 + 16 + c) * HN, ahi[1], alo[1], g);

    #pragma unroll
    for (int mi = 0; mi < 3; ++mi) {
        f32x4 acc[2][8];
        #pragma unroll
        for (int i = 0; i < 2; ++i)
            #pragma unroll
            for (int n = 0; n < 8; ++n) acc[i][n] = (f32x4){0.f, 0.f, 0.f, 0.f};
        mlp_layer2(acc, ahi, alo, Whi, Wlo, 8 + mi, lane);
        float* dst = (mi == 0) ? Ps : (mi == 1) ? Pr : Pn;
        #pragma unroll
        for (int n = 0; n < 8; ++n) {
            int col = 16*n + c;
            float bv = (mi == 0) ? eb0[col] : (mi == 2) ? nb0[col] : 0.0f;
            #pragma unroll
            for (int i = 0; i < 2; ++i)
                #pragma unroll
                for (int j = 0; j < 4; ++j) {
                    size_t row = (size_t)(n0 + 16*i + 4*g + j);
                    dst[row*HN + col] = acc[i][n][j] + bv;
                }
        }
    }
}

// ---------------- edge block: 32 edges/wave, fused 4 layers + LN + residual + scatter ----------------
__global__ __launch_bounds__(256, 2)
void edge_kernel(const float* __restrict__ ea, const int* __restrict__ eidx,
                 const float* __restrict__ Ps, const float* __restrict__ Pr,
                 const unsigned short* __restrict__ Whi, const unsigned short* __restrict__ Wlo,
                 const float* __restrict__ eb1, const float* __restrict__ eb2,
                 const float* __restrict__ eb3, const float* __restrict__ eg,
                 const float* __restrict__ ebt,
                 float* __restrict__ agg, float* __restrict__ out) {
    __shared__ float xp[4 * 16 * HN];      // 8KB per wave, wave-private
    int w = threadIdx.x >> 6, lane = threadIdx.x & 63;
    int g = lane >> 4, c = lane & 15;
    int e0 = (blockIdx.x * 4 + w) * 32;
    if (e0 >= NEDGES) return;              // no barriers anywhere -> safe
    float* buf = xp + w * (16 * HN);
    const int* senders = eidx;
    const int* receivers = eidx + NEDGES;

    short8 ahi[2][4], alo[2][4];
    load_frags_global(ea + (size_t)(e0 + c) * HN, ahi[0], alo[0], g);
    load_frags_global(ea + (size_t)(e0 + 16 + c) * HN, ahi[1], alo[1], g);

    f32x4 C[2][8];
    #pragma unroll
    for (int i = 0; i < 2; ++i)
        #pragma unroll
        for (int n = 0; n < 8; ++n) C[i][n] = (f32x4){0.f, 0.f, 0.f, 0.f};

    // layer 0: ea @ W0c  (+ gathered Ps[s] + Pr[r] carrying na@W0a+eb0, na@W0b)
    mlp_layer2(C, ahi, alo, Whi, Wlo, 0, lane);

    int sid[2][4], rid[2][4];
    #pragma unroll
    for (int i = 0; i < 2; ++i)
        #pragma unroll
        for (int j = 0; j < 4; ++j) {
            int e = e0 + 16*i + 4*g + j;
            sid[i][j] = senders[e];
            rid[i][j] = receivers[e];
        }
    #pragma unroll
    for (int n = 0; n < 8; ++n) {
        int col = 16*n + c;
        #pragma unroll
        for (int i = 0; i < 2; ++i)
            #pragma unroll
            for (int j = 0; j < 4; ++j)
                C[i][n][j] = fmaxf(C[i][n][j] + Ps[(size_t)sid[i][j]*HN + col]
                                              + Pr[(size_t)rid[i][j]*HN + col], 0.0f);
    }
    #pragma unroll
    for (int i = 0; i < 2; ++i) {          // sequential reuse of wave-private buf (DS in-order)
        c_to_lds(buf, C[i], g, c);
        lds_to_frags(buf, ahi[i], alo[i], g, c);
    }

    #pragma unroll
    for (int L = 1; L <= 2; ++L) {
        #pragma unroll
        for (int i = 0; i < 2; ++i)
            #pragma unroll
            for (int n = 0; n < 8; ++n) C[i][n] = (f32x4){0.f, 0.f, 0.f, 0.f};
        mlp_layer2(C, ahi, alo, Whi, Wlo, L, lane);
        #pragma unroll
        for (int i = 0; i < 2; ++i) {
            add_bias_act(C[i], (L == 1) ? eb1 : eb2, c, true);
            c_to_lds(buf, C[i], g, c);
            lds_to_frags(buf, ahi[i], alo[i], g, c);
        }
    }

    #pragma unroll
    for (int i = 0; i < 2; ++i)
        #pragma unroll
        for (int n = 0; n < 8; ++n) C[i][n] = (f32x4){0.f, 0.f, 0.f, 0.f};
    mlp_layer2(C, ahi, alo, Whi, Wlo, 3, lane);
    #pragma unroll
    for (int i = 0; i < 2; ++i) {
        add_bias_act(C[i], eb3, c, false);
        apply_ln(C[i], eg, ebt, c);
    }

    // scatter-add ue into agg + write ue + edge_attr to output
    #pragma unroll
    for (int n = 0; n < 8; ++n) {
        int col = 16*n + c;
        #pragma unroll
        for (int i = 0; i < 2; ++i)
            #pragma unroll
            for (int j = 0; j < 4; ++j) {
                size_t e = (size_t)(e0 + 16*i + 4*g + j);
                float v = C[i][n][j];
                unsafeAtomicAdd(&agg[(size_t)rid[i][j]*HN + col], v);
                out[((size_t)NNODES + e)*HN + col] = v + ea[e*HN + col];
            }
    }
}

// ---------------- node block: 32 nodes/wave, fused 4 layers + LN + residual ----------------
__global__ __launch_bounds__(256, 2)
void node_kernel(const float* __restrict__ na, const float* __restrict__ agg,
                 const float* __restrict__ Pn,
                 const unsigned short* __restrict__ Whi, const unsigned short* __restrict__ Wlo,
                 const float* __restrict__ nb1, const float* __restrict__ nb2,
                 const float* __restrict__ nb3, const float* __restrict__ ng,
                 const float* __restrict__ nbt,
                 float* __restrict__ out) {
    __shared__ float xp[4 * 16 * HN];
    int w = threadIdx.x >> 6, lane = threadIdx.x & 63;
    int g = lane >> 4, c = lane & 15;
    int n0 = (blockIdx.x * 4 + w) * 32;
    if (n0 >= NNODES) return;              // 100000 % 32 == 0 -> uniform, no barriers
    float* buf = xp + w * (16 * HN);

    short8 ahi[2][4], alo[2][4];
    load_frags_global(agg + (size_t)(n0 + c) * HN, ahi[0], alo[0], g);
    load_frags_global(agg + (size_t)(n0 + 16 + c) * HN, ahi[1], alo[1], g);

    f32x4 C[2][8];
    #pragma unroll
    for (int i = 0; i < 2; ++i)
        #pragma unroll
        for (int n = 0; n < 8; ++n) C[i][n] = (f32x4){0.f, 0.f, 0.f, 0.f};

    // layer 0: agg @ nw0b + Pn (Pn carries na@nw0a + nb0)
    mlp_layer2(C, ahi, alo, Whi, Wlo, 4, lane);
    #pragma unroll
    for (int n = 0; n < 8; ++n) {
        int col = 16*n + c;
        #pragma unroll
        for (int i = 0; i < 2; ++i)
            #pragma unroll
            for (int j = 0; j < 4; ++j)
                C[i][n][j] = fmaxf(C[i][n][j] + Pn[(size_t)(n0 + 16*i + 4*g + j)*HN + col], 0.0f);
    }
    #pragma unroll
    for (int i = 0; i < 2; ++i) {
        c_to_lds(buf, C[i], g, c);
        lds_to_frags(buf, ahi[i], alo[i], g, c);
    }

    #pragma unroll
    for (int L = 5; L <= 6; ++L) {
        #pragma unroll
        for (int i = 0; i < 2; ++i)
            #pragma unroll
            for (int n = 0; n < 8; ++n) C[i][n] = (f32x4){0.f, 0.f, 0.f, 0.f};
        mlp_layer2(C, ahi, alo, Whi, Wlo, L, lane);
        #pragma unroll
        for (int i = 0; i < 2; ++i) {
            add_bias_act(C[i], (L == 5) ? nb1 : nb2, c, true);
            c_to_lds(buf, C[i], g, c);
            lds_to_frags(buf, ahi[i], alo[i], g, c);
        }
    }

    #pragma unroll
    for (int i = 0; i < 2; ++i)
        #pragma unroll
        for (int n = 0; n < 8; ++n) C[i][n] = (f32x4){0.f, 0.f, 0.f, 0.f};
    mlp_layer2(C, ahi, alo, Whi, Wlo, 7, lane);
    #pragma unroll
    for (int i = 0; i < 2; ++i) {
        add_bias_act(C[i], nb3, c, false);
        apply_ln(C[i], ng, nbt, c);
    }

    #pragma unroll
    for (int n = 0; n < 8; ++n) {
        int col = 16*n + c;
        #pragma unroll
        for (int i = 0; i < 2; ++i)
            #pragma unroll
            for (int j = 0; j < 4; ++j) {
                size_t row = (size_t)(n0 + 16*i + 4*g + j);
                out[row*HN + col] = C[i][n][j] + na[row*HN + col];
            }
    }
}

extern "C" void kernel_launch(void* const* d_in, const int* in_sizes, int n_in,
                              void* d_out, int out_size, void* d_ws, size_t ws_size,
                              hipStream_t stream) {
    const float* node_attr = (const float*)d_in[0];
    const float* edge_attr = (const float*)d_in[1];
    const int*   edge_index = (const int*)d_in[2];
    // d_in[3] = num_nodes scalar (unused; fixed sizes)
    const float* ew0 = (const float*)d_in[4];
    const float* eb0 = (const float*)d_in[5];
    const float* ew1 = (const float*)d_in[6];
    const float* eb1 = (const float*)d_in[7];
    const float* ew2 = (const float*)d_in[8];
    const float* eb2 = (const float*)d_in[9];
    const float* ew3 = (const float*)d_in[10];
    const float* eb3 = (const float*)d_in[11];
    const float* eg  = (const float*)d_in[12];
    const float* ebt = (const float*)d_in[13];
    const float* nw0 = (const float*)d_in[14];
    const float* nb0 = (const float*)d_in[15];
    const float* nw1 = (const float*)d_in[16];
    const float* nb1 = (const float*)d_in[17];
    const float* nw2 = (const float*)d_in[18];
    const float* nb2 = (const float*)d_in[19];
    const float* nw3 = (const float*)d_in[20];
    const float* nb3 = (const float*)d_in[21];
    const float* ng  = (const float*)d_in[22];
    const float* nbt = (const float*)d_in[23];
    float* out = (float*)d_out;

    const size_t NH = (size_t)NNODES * HN * sizeof(float);   // 51.2 MB
    char* ws = (char*)d_ws;
    float* agg = (float*)(ws);
    float* Ps  = (float*)(ws + NH);
    float* Pr  = (float*)(ws + 2*NH);
    float* Pn  = (float*)(ws + 3*NH);
    unsigned short* Whi = (unsigned short*)(ws + 4*NH);
    unsigned short* Wlo = Whi + (size_t)11 * 2048 * 8;

    hipMemsetAsync(agg, 0, NH, stream);
    prep_weights<<<88, 256, 0, stream>>>(ew0, ew1, ew2, ew3, nw0, nw1, nw2, nw3, Whi, Wlo);

    int preWaves  = NNODES / 32;                      // 3125
    int edgeWaves = NEDGES / 32;                      // 18750
    int nodeWaves = NNODES / 32;                      // 3125
    pre_kernel<<<(preWaves + 3)/4, 256, 0, stream>>>(node_attr, eb0, nb0, Whi, Wlo, Ps, Pr, Pn);
    edge_kernel<<<(edgeWaves + 3)/4, 256, 0, stream>>>(edge_attr, edge_index, Ps, Pr, Whi, Wlo,
                                                       eb1, eb2, eb3, eg, ebt, agg, out);
    node_kernel<<<(nodeWaves + 3)/4, 256, 0, stream>>>(node_attr, agg, Pn, Whi, Wlo,
                                                       nb1, nb2, nb3, ng, nbt, out);
}

// Round 3
// 1520.060 us; speedup vs baseline: 1.1041x; 1.1041x over previous
//
#include <hip/hip_runtime.h>

#define HN 128
#define NNODES 100000
#define NEDGES 600000

typedef __attribute__((ext_vector_type(8))) short short8;
typedef __attribute__((ext_vector_type(4))) float f32x4;

// ---------- bf16 split helpers (x ~= hi + lo, dropped term ~2^-16 rel) ----------
__device__ __forceinline__ unsigned short f2bf(float x) {
    unsigned u = __float_as_uint(x);
    u += 0x7FFFu + ((u >> 16) & 1u);   // round-to-nearest-even
    return (unsigned short)(u >> 16);
}
__device__ __forceinline__ float bf2f(unsigned short h) {
    return __uint_as_float(((unsigned)h) << 16);
}

__device__ __forceinline__ f32x4 mfma16(short8 a, short8 b, f32x4 c) {
    return __builtin_amdgcn_mfma_f32_16x16x32_bf16(a, b, c, 0, 0, 0);
}

__device__ __forceinline__ void split_frag(const float xs[8], short8 &hi, short8 &lo) {
    #pragma unroll
    for (int e = 0; e < 8; ++e) {
        unsigned short h = f2bf(xs[e]);
        hi[e] = (short)h;
        lo[e] = (short)f2bf(xs[e] - bf2f(h));
    }
}

// A-frag layout (mfma_f32_16x16x32_bf16): row = lane&15, k = 8*(lane>>4)+e (+32*t)
__device__ __forceinline__ void load_frags_global(const float* __restrict__ row,
                                                  short8 ahi[4], short8 alo[4], int g) {
    #pragma unroll
    for (int t = 0; t < 4; ++t) {
        float4 v0 = *(const float4*)(row + 32*t + 8*g);
        float4 v1 = *(const float4*)(row + 32*t + 8*g + 4);
        float xs[8] = {v0.x, v0.y, v0.z, v0.w, v1.x, v1.y, v1.z, v1.w};
        split_frag(xs, ahi[t], alo[t]);
    }
}

// one 128x128 layer, 16 rows/wave. All 8 (bh,bl) pairs of a t-step preloaded
// (16 clustered global loads -> one amortized latency exposure), then 24 MFMAs.
__device__ __forceinline__ void mlp_layer16(f32x4 C[8], const short8 ahi[4], const short8 alo[4],
                                            const unsigned short* __restrict__ Whi,
                                            const unsigned short* __restrict__ Wlo,
                                            int mat, int lane) {
    #pragma unroll
    for (int t = 0; t < 4; ++t) {
        short8 bh[8], bl[8];
        #pragma unroll
        for (int n = 0; n < 8; ++n) {
            size_t idx = ((size_t)((mat*32 + t*8 + n)*64 + lane)) * 8;
            bh[n] = *(const short8*)(Whi + idx);
            bl[n] = *(const short8*)(Wlo + idx);
        }
        #pragma unroll
        for (int n = 0; n < 8; ++n) {
            f32x4 a = C[n];
            a = mfma16(ahi[t], bh[n], a);
            a = mfma16(ahi[t], bl[n], a);
            a = mfma16(alo[t], bh[n], a);
            C[n] = a;
        }
    }
}

// C/D layout: col = lane&15 (+16n), row = 4*(lane>>4)+j.  XOR-swizzled f32 LDS transpose.
// buf is PER-WAVE (8KB) -> no __syncthreads needed; DS ops retire in order within a wave.
__device__ __forceinline__ void c_to_lds(float* buf, const f32x4 C[8], int g, int c) {
    #pragma unroll
    for (int n = 0; n < 8; ++n) {
        #pragma unroll
        for (int j = 0; j < 4; ++j) {
            int row = 4*g + j;
            int col = 16*n + c;
            buf[(row*HN + col) ^ ((row & 7) << 2)] = C[n][j];
        }
    }
}
__device__ __forceinline__ void lds_to_frags(const float* buf, short8 ahi[4], short8 alo[4],
                                             int g, int c) {
    #pragma unroll
    for (int t = 0; t < 4; ++t) {
        int w0 = c*HN + 32*t + 8*g;
        int x  = (c & 7) << 2;
        float4 v0 = *(const float4*)(buf + (w0 ^ x));
        float4 v1 = *(const float4*)(buf + ((w0 + 4) ^ x));
        float xs[8] = {v0.x, v0.y, v0.z, v0.w, v1.x, v1.y, v1.z, v1.w};
        split_frag(xs, ahi[t], alo[t]);
    }
}

__device__ __forceinline__ void add_bias_act(f32x4 C[8], const float* __restrict__ b,
                                             int c, bool do_relu) {
    #pragma unroll
    for (int n = 0; n < 8; ++n) {
        float bv = b[16*n + c];
        #pragma unroll
        for (int j = 0; j < 4; ++j) {
            float v = C[n][j] + bv;
            C[n][j] = do_relu ? fmaxf(v, 0.0f) : v;
        }
    }
}

__device__ __forceinline__ void apply_ln(f32x4 C[8], const float* __restrict__ gamma,
                                         const float* __restrict__ beta, int c) {
    float s1[4] = {0.f,0.f,0.f,0.f}, s2[4] = {0.f,0.f,0.f,0.f};
    #pragma unroll
    for (int n = 0; n < 8; ++n)
        #pragma unroll
        for (int j = 0; j < 4; ++j) { float v = C[n][j]; s1[j] += v; s2[j] += v*v; }
    #pragma unroll
    for (int m = 1; m < 16; m <<= 1) {
        #pragma unroll
        for (int j = 0; j < 4; ++j) {
            s1[j] += __shfl_xor(s1[j], m);
            s2[j] += __shfl_xor(s2[j], m);
        }
    }
    float mn[4], rs[4];
    #pragma unroll
    for (int j = 0; j < 4; ++j) {
        mn[j] = s1[j] * (1.0f/128.0f);
        float var = s2[j] * (1.0f/128.0f) - mn[j]*mn[j];
        rs[j] = rsqrtf(var + 1e-5f);
    }
    #pragma unroll
    for (int n = 0; n < 8; ++n) {
        float ga = gamma[16*n + c], be = beta[16*n + c];
        #pragma unroll
        for (int j = 0; j < 4; ++j)
            C[n][j] = (C[n][j] - mn[j]) * rs[j] * ga + be;
    }
}

// ---------------- weight prep: 11 matrices of [128,128] -> B-frag layout ----------------
// mat ids: 0=ew0[256:384] 1=ew1 2=ew2 3=ew3 | 4=nw0[128:256] 5=nw1 6=nw2 7=nw3
//          8=ew0[0:128](Ps) 9=ew0[128:256](Pr) 10=nw0[0:128](Pn)
__global__ void prep_weights(const float* __restrict__ ew0, const float* __restrict__ ew1,
                             const float* __restrict__ ew2, const float* __restrict__ ew3,
                             const float* __restrict__ nw0, const float* __restrict__ nw1,
                             const float* __restrict__ nw2, const float* __restrict__ nw3,
                             unsigned short* __restrict__ Whi, unsigned short* __restrict__ Wlo) {
    int gid = blockIdx.x * blockDim.x + threadIdx.x;
    if (gid >= 11*2048) return;
    int lane = gid & 63;
    int n = (gid >> 6) & 7;
    int t = (gid >> 9) & 3;
    int m = gid >> 11;
    const float* src; int roff = 0;
    switch (m) {
        case 0: src = ew0; roff = 256; break;
        case 1: src = ew1; break;
        case 2: src = ew2; break;
        case 3: src = ew3; break;
        case 4: src = nw0; roff = 128; break;
        case 5: src = nw1; break;
        case 6: src = nw2; break;
        case 7: src = nw3; break;
        case 8: src = ew0; roff = 0; break;
        case 9: src = ew0; roff = 128; break;
        default: src = nw0; roff = 0; break;
    }
    int col = 16*n + (lane & 15);
    int rbase = roff + 32*t + 8*(lane >> 4);
    size_t o = (size_t)gid * 8;
    #pragma unroll
    for (int e = 0; e < 8; ++e) {
        float x = src[(size_t)(rbase + e) * HN + col];
        unsigned short h = f2bf(x);
        Whi[o + e] = h;
        Wlo[o + e] = f2bf(x - bf2f(h));
    }
}

// ---------------- pre-GEMM: Ps = na@W0a+eb0, Pr = na@W0b, Pn = na@nw0a+nb0 ----------------
// 16 rows/wave; no barriers -> early-out safe.
__global__ __launch_bounds__(256, 3)
void pre_kernel(const float* __restrict__ na, const float* __restrict__ eb0,
                const float* __restrict__ nb0,
                const unsigned short* __restrict__ Whi, const unsigned short* __restrict__ Wlo,
                float* __restrict__ Ps, float* __restrict__ Pr, float* __restrict__ Pn) {
    int w = threadIdx.x >> 6, lane = threadIdx.x & 63;
    int g = lane >> 4, c = lane & 15;
    int n0 = (blockIdx.x * 4 + w) * 16;
    if (n0 >= NNODES) return;

    short8 ahi[4], alo[4];
    load_frags_global(na + (size_t)(n0 + c) * HN, ahi, alo, g);

    #pragma unroll
    for (int mi = 0; mi < 3; ++mi) {
        f32x4 acc[8];
        #pragma unroll
        for (int n = 0; n < 8; ++n) acc[n] = (f32x4){0.f, 0.f, 0.f, 0.f};
        mlp_layer16(acc, ahi, alo, Whi, Wlo, 8 + mi, lane);
        float* dst = (mi == 0) ? Ps : (mi == 1) ? Pr : Pn;
        #pragma unroll
        for (int n = 0; n < 8; ++n) {
            int col = 16*n + c;
            float bv = (mi == 0) ? eb0[col] : (mi == 2) ? nb0[col] : 0.0f;
            #pragma unroll
            for (int j = 0; j < 4; ++j)
                dst[(size_t)(n0 + 4*g + j)*HN + col] = acc[n][j] + bv;
        }
    }
}

// ---------------- edge block: 16 edges/wave, fused 4 layers + LN + residual + scatter ----------------
__global__ __launch_bounds__(256, 3)
void edge_kernel(const float* __restrict__ ea, const int* __restrict__ eidx,
                 const float* __restrict__ Ps, const float* __restrict__ Pr,
                 const unsigned short* __restrict__ Whi, const unsigned short* __restrict__ Wlo,
                 const float* __restrict__ eb1, const float* __restrict__ eb2,
                 const float* __restrict__ eb3, const float* __restrict__ eg,
                 const float* __restrict__ ebt,
                 float* __restrict__ agg, float* __restrict__ out) {
    __shared__ float xp[4 * 16 * HN];      // 8KB per wave, wave-private -> no barriers
    int w = threadIdx.x >> 6, lane = threadIdx.x & 63;
    int g = lane >> 4, c = lane & 15;
    int e0 = (blockIdx.x * 4 + w) * 16;
    if (e0 >= NEDGES) return;
    float* buf = xp + w * (16 * HN);
    const int* senders = eidx;
    const int* receivers = eidx + NEDGES;

    short8 ahi[4], alo[4];
    load_frags_global(ea + (size_t)(e0 + c) * HN, ahi, alo, g);

    int sid[4], rid[4];
    #pragma unroll
    for (int j = 0; j < 4; ++j) {
        int e = e0 + 4*g + j;
        sid[j] = senders[e];
        rid[j] = receivers[e];
    }

    f32x4 C[8];
    #pragma unroll
    for (int n = 0; n < 8; ++n) C[n] = (f32x4){0.f, 0.f, 0.f, 0.f};

    // layer 0: ea @ W0c (+ gathered Ps[s] + Pr[r] carrying na@W0a+eb0, na@W0b)
    mlp_layer16(C, ahi, alo, Whi, Wlo, 0, lane);

    // gather-add, clustered in 32-load bursts via pv staging
    #pragma unroll
    for (int nh = 0; nh < 2; ++nh) {
        float pv[16];
        #pragma unroll
        for (int n = 0; n < 4; ++n)
            #pragma unroll
            for (int j = 0; j < 4; ++j) {
                int col = 16*(4*nh + n) + c;
                pv[n*4 + j] = Ps[(size_t)sid[j]*HN + col] + Pr[(size_t)rid[j]*HN + col];
            }
        #pragma unroll
        for (int n = 0; n < 4; ++n)
            #pragma unroll
            for (int j = 0; j < 4; ++j) {
                int nn = 4*nh + n;
                C[nn][j] = fmaxf(C[nn][j] + pv[n*4 + j], 0.0f);
            }
    }
    c_to_lds(buf, C, g, c);
    lds_to_frags(buf, ahi, alo, g, c);

    #pragma unroll
    for (int L = 1; L <= 2; ++L) {
        #pragma unroll
        for (int n = 0; n < 8; ++n) C[n] = (f32x4){0.f, 0.f, 0.f, 0.f};
        mlp_layer16(C, ahi, alo, Whi, Wlo, L, lane);
        add_bias_act(C, (L == 1) ? eb1 : eb2, c, true);
        c_to_lds(buf, C, g, c);
        lds_to_frags(buf, ahi, alo, g, c);
    }

    #pragma unroll
    for (int n = 0; n < 8; ++n) C[n] = (f32x4){0.f, 0.f, 0.f, 0.f};
    mlp_layer16(C, ahi, alo, Whi, Wlo, 3, lane);
    add_bias_act(C, eb3, c, false);
    apply_ln(C, eg, ebt, c);

    // scatter-add ue into agg + write ue + edge_attr to output
    #pragma unroll
    for (int n = 0; n < 8; ++n) {
        int col = 16*n + c;
        #pragma unroll
        for (int j = 0; j < 4; ++j) {
            size_t e = (size_t)(e0 + 4*g + j);
            float v = C[n][j];
            unsafeAtomicAdd(&agg[(size_t)rid[j]*HN + col], v);
            out[((size_t)NNODES + e)*HN + col] = v + ea[e*HN + col];
        }
    }
}

// ---------------- node block: 16 nodes/wave, fused 4 layers + LN + residual ----------------
__global__ __launch_bounds__(256, 3)
void node_kernel(const float* __restrict__ na, const float* __restrict__ agg,
                 const float* __restrict__ Pn,
                 const unsigned short* __restrict__ Whi, const unsigned short* __restrict__ Wlo,
                 const float* __restrict__ nb1, const float* __restrict__ nb2,
                 const float* __restrict__ nb3, const float* __restrict__ ng,
                 const float* __restrict__ nbt,
                 float* __restrict__ out) {
    __shared__ float xp[4 * 16 * HN];
    int w = threadIdx.x >> 6, lane = threadIdx.x & 63;
    int g = lane >> 4, c = lane & 15;
    int n0 = (blockIdx.x * 4 + w) * 16;
    if (n0 >= NNODES) return;
    float* buf = xp + w * (16 * HN);

    short8 ahi[4], alo[4];
    load_frags_global(agg + (size_t)(n0 + c) * HN, ahi, alo, g);

    f32x4 C[8];
    #pragma unroll
    for (int n = 0; n < 8; ++n) C[n] = (f32x4){0.f, 0.f, 0.f, 0.f};

    // layer 0: agg @ nw0b + Pn (Pn carries na@nw0a + nb0)
    mlp_layer16(C, ahi, alo, Whi, Wlo, 4, lane);
    #pragma unroll
    for (int n = 0; n < 8; ++n) {
        int col = 16*n + c;
        #pragma unroll
        for (int j = 0; j < 4; ++j)
            C[n][j] = fmaxf(C[n][j] + Pn[(size_t)(n0 + 4*g + j)*HN + col], 0.0f);
    }
    c_to_lds(buf, C, g, c);
    lds_to_frags(buf, ahi, alo, g, c);

    #pragma unroll
    for (int L = 5; L <= 6; ++L) {
        #pragma unroll
        for (int n = 0; n < 8; ++n) C[n] = (f32x4){0.f, 0.f, 0.f, 0.f};
        mlp_layer16(C, ahi, alo, Whi, Wlo, L, lane);
        add_bias_act(C, (L == 5) ? nb1 : nb2, c, true);
        c_to_lds(buf, C, g, c);
        lds_to_frags(buf, ahi, alo, g, c);
    }

    #pragma unroll
    for (int n = 0; n < 8; ++n) C[n] = (f32x4){0.f, 0.f, 0.f, 0.f};
    mlp_layer16(C, ahi, alo, Whi, Wlo, 7, lane);
    add_bias_act(C, nb3, c, false);
    apply_ln(C, ng, nbt, c);

    #pragma unroll
    for (int n = 0; n < 8; ++n) {
        int col = 16*n + c;
        #pragma unroll
        for (int j = 0; j < 4; ++j) {
            size_t row = (size_t)(n0 + 4*g + j);
            out[row*HN + col] = C[n][j] + na[row*HN + col];
        }
    }
}

extern "C" void kernel_launch(void* const* d_in, const int* in_sizes, int n_in,
                              void* d_out, int out_size, void* d_ws, size_t ws_size,
                              hipStream_t stream) {
    const float* node_attr = (const float*)d_in[0];
    const float* edge_attr = (const float*)d_in[1];
    const int*   edge_index = (const int*)d_in[2];
    // d_in[3] = num_nodes scalar (unused; fixed sizes)
    const float* ew0 = (const float*)d_in[4];
    const float* eb0 = (const float*)d_in[5];
    const float* ew1 = (const float*)d_in[6];
    const float* eb1 = (const float*)d_in[7];
    const float* ew2 = (const float*)d_in[8];
    const float* eb2 = (const float*)d_in[9];
    const float* ew3 = (const float*)d_in[10];
    const float* eb3 = (const float*)d_in[11];
    const float* eg  = (const float*)d_in[12];
    const float* ebt = (const float*)d_in[13];
    const float* nw0 = (const float*)d_in[14];
    const float* nb0 = (const float*)d_in[15];
    const float* nw1 = (const float*)d_in[16];
    const float* nb1 = (const float*)d_in[17];
    const float* nw2 = (const float*)d_in[18];
    const float* nb2 = (const float*)d_in[19];
    const float* nw3 = (const float*)d_in[20];
    const float* nb3 = (const float*)d_in[21];
    const float* ng  = (const float*)d_in[22];
    const float* nbt = (const float*)d_in[23];
    float* out = (float*)d_out;

    const size_t NH = (size_t)NNODES * HN * sizeof(float);   // 51.2 MB
    char* ws = (char*)d_ws;
    float* agg = (float*)(ws);
    float* Ps  = (float*)(ws + NH);
    float* Pr  = (float*)(ws + 2*NH);
    float* Pn  = (float*)(ws + 3*NH);
    unsigned short* Whi = (unsigned short*)(ws + 4*NH);
    unsigned short* Wlo = Whi + (size_t)11 * 2048 * 8;

    hipMemsetAsync(agg, 0, NH, stream);
    prep_weights<<<88, 256, 0, stream>>>(ew0, ew1, ew2, ew3, nw0, nw1, nw2, nw3, Whi, Wlo);

    int preWaves  = NNODES / 16;                      // 6250
    int edgeWaves = NEDGES / 16;                      // 37500
    pre_kernel<<<(preWaves + 3)/4, 256, 0, stream>>>(node_attr, eb0, nb0, Whi, Wlo, Ps, Pr, Pn);
    edge_kernel<<<(edgeWaves + 3)/4, 256, 0, stream>>>(edge_attr, edge_index, Ps, Pr, Whi, Wlo,
                                                       eb1, eb2, eb3, eg, ebt, agg, out);
    node_kernel<<<(preWaves + 3)/4, 256, 0, stream>>>(node_attr, agg, Pn, Whi, Wlo,
                                                      nb1, nb2, nb3, ng, nbt, out);
}